// Round 12
// baseline (10.279 us; speedup 1.0000x reference)
//
#include <hip/hip_runtime.h>
#include <math.h>

#define NH 32   // modes (N/2)

typedef _Float16 f16;
typedef _Float16 f16x2 __attribute__((ext_vector_type(2)));
typedef _Float16 f16x4 __attribute__((ext_vector_type(4)));
typedef float    f32x2 __attribute__((ext_vector_type(2)));
typedef float    f32x4 __attribute__((ext_vector_type(4)));

// Reduce x mod 2*pi to [-pi, pi], 2-term float Cody-Waite.
// PI2_HI = 6.28125 (8-bit mantissa) -> k*PI2_HI exact for k < 2^16.
__device__ __forceinline__ float reduce2pi(float x) {
    const float INV2PI = 0.15915494309189535f;
    const float PI2_HI = 6.28125f;
    const float PI2_LO = 1.9353071795864769e-3f;
    float k = rintf(x * INV2PI);
    float r = fmaf(-k, PI2_HI, x);
    r = fmaf(-k, PI2_LO, r);
    return r;
}

// Vandermonde-factored S4D: l = 128a + b (a<32, b<128)
//   K[h,l] = sum_n Re(G[n,a] * W[n,b]),  G = c_eff*u^a (u=z^128), W = z^b
// One block per h. Matmul D[b][a] = sum_k X[b][k]*Y[k][a], k interleaved
// complex (k=2n -> Wr,Gr; k=2n+1 -> Wi,-Gi); fragment mappings validated
// R7-R11 (absmax at f16-rounding level).
// R12: ZERO __syncthreads. Every dependency is wave-local:
//  - W slice [32wv,32wv+32) built and consumed by the same wave (R11 already).
//  - G: each wave redundantly builds the FULL 32x32 Alds with all 64 lanes
//    (identical bits from identical code/inputs -> benign same-value race,
//    deterministic).
//  - Epilogue: wave wv stores only its own b-slice of s_out (cols it wrote),
//    f32x2/lane -> 128-B aligned full-line chunks.
// Waves run start-to-finish independently; 16 waves/CU self-overlap.
__global__ __launch_bounds__(256, 4) void s4d_kernel(
    const float* __restrict__ log_dt,
    const float* __restrict__ Cv,          // (H, 32, 2)
    const float* __restrict__ log_A_real,  // (H, 32)
    const float* __restrict__ A_imag,      // (H, 32)
    float* __restrict__ Kout,              // (H, L), L = 4096
    int L)
{
    const int h    = blockIdx.x;
    const int tid  = threadIdx.x;
    const int lane = tid & 63;
    const int wv   = tid >> 6;       // wave id 0..3

    __shared__ f16 Alds[32][68];     // Y: [a][k]  k=2n -> Gr, k=2n+1 -> -Gi
    __shared__ f16 Wlds[128][68];    // X: [b][k]  k=2n -> Wr, k=2n+1 -> Wi
    __shared__ float s_out[32][132]; // staged D[a][b]

    // ---- W build: thread = (mode n, 16 consecutive b); wave-local slice ----
    {
        const int n  = tid & 31;
        const int bg = tid >> 5;                 // in {2wv, 2wv+1}
        const float dt  = __expf(log_dt[h]);
        const float Ar  = -__expf(log_A_real[h * NH + n]);
        const float Ai  = A_imag[h * NH + n];
        const float dar = Ar * dt;
        const float dai = Ai * dt;
        float zr, zi;
        {
            float e = __expf(dar);
            float sn, cs; __sincosf(dai, &sn, &cs);   // |dai| <= ~9.8
            zr = e * cs;  zi = e * sn;
        }
        const float b0f = (float)(bg * 16);
        float e0 = __expf(dar * b0f);
        float sn, cs; __sincosf(reduce2pi(dai * b0f), &sn, &cs);
        float wr = e0 * cs, wi = e0 * sn;        // W(n, b0)
        #pragma unroll
        for (int i = 0; i < 16; ++i) {
            const int b = bg * 16 + i;
            f16x2 pw = { (f16)wr, (f16)wi };
            *reinterpret_cast<f16x2*>(&Wlds[b][2 * n]) = pw;
            float t = wr * zr - wi * zi;         // w *= z
            wi = wr * zi + wi * zr;
            wr = t;
        }
    }

    // ---- G build: EVERY wave builds full Alds (all 64 lanes) ----
    // lanes 0-31: a = 0..15 (seed 1); lanes 32-63: a = 16..31 (seed z^2048).
    {
        const int n  = lane & 31;
        const int ah = (lane >> 5) * 16;
        const float dt  = __expf(log_dt[h]);
        const float Ar  = -__expf(log_A_real[h * NH + n]);
        const float Ai  = A_imag[h * NH + n];
        const float dar = Ar * dt;
        const float dai = Ai * dt;
        float zr, zi;
        {
            float e = __expf(dar);
            float sn, cs; __sincosf(dai, &sn, &cs);
            zr = e * cs;  zi = e * sn;
        }
        // c_eff = 2 * C * (z - 1)/A
        float edr = zr - 1.0f, edi = zi;
        float inv = 1.0f / fmaf(Ar, Ar, Ai * Ai);
        float fr  = (edr * Ar + edi * Ai) * inv;
        float fi  = (edi * Ar - edr * Ai) * inv;
        float cr  = Cv[(h * NH + n) * 2 + 0];
        float ci  = Cv[(h * NH + n) * 2 + 1];
        float cer = 2.0f * (cr * fr - ci * fi);
        float cei = 2.0f * (cr * fi + ci * fr);
        // u = z^128; seed = z^(128*ah), S in {0, 2048}: exact scalings
        float eu = __expf(dar * 128.0f);
        float su, cu; __sincosf(reduce2pi(dai * 128.0f), &su, &cu);
        float ur = eu * cu, ui = eu * su;
        const float S = (float)(128 * ah);
        float es = __expf(dar * S);              // may underflow -> mode dead
        float ss, sc; __sincosf(reduce2pi(dai * S), &ss, &sc);
        float br = es * sc, bi = es * ss;
        float gr = cer * br - cei * bi;
        float gi = cer * bi + cei * br;
        #pragma unroll
        for (int s = 0; s < 16; ++s) {
            const int a = ah + s;
            f16x2 pg = { (f16)gr, (f16)(-gi) };
            *reinterpret_cast<f16x2*>(&Alds[a][2 * n]) = pg;
            float t = gr * ur - gi * ui;         // g *= u
            gi = gr * ui + gi * ur;
            gr = t;
        }
    }
    __builtin_amdgcn_wave_barrier();   // scheduling fence; lgkmcnt orders LDS

    // ---- MFMA -> stage D in LDS (all deps wave-local) ----
    // X-frag: lane holds X[b = 32wv+16mi + (l&15)][k = 16ks + 4(l>>4) + j]
    // Y-frag: lane holds Y[k = 16ks + 4(l>>4) + j][a = 16ni + (l&15)]
    // D:      lane holds D[b = 32wv+16mi + 4(l>>4)+reg][a = 16ni + (l&15)]
    const int r = lane & 15;
    const int q = lane >> 4;
    #pragma unroll
    for (int mi = 0; mi < 2; ++mi) {
        #pragma unroll
        for (int ni = 0; ni < 2; ++ni) {
            f32x4 acc = {0.f, 0.f, 0.f, 0.f};
            #pragma unroll
            for (int ks = 0; ks < 4; ++ks) {
                f16x4 xf = *(const f16x4*)&Wlds[32 * wv + 16 * mi + r][16 * ks + 4 * q];
                f16x4 yf = *(const f16x4*)&Alds[16 * ni + r][16 * ks + 4 * q];
                acc = __builtin_amdgcn_mfma_f32_16x16x16f16(xf, yf, acc, 0, 0, 0);
            }
            const int a  = 16 * ni + r;
            const int b0 = 32 * wv + 16 * mi + 4 * q;   // 16-B aligned
            *(f32x4*)&s_out[a][b0] = acc;
        }
    }
    __builtin_amdgcn_wave_barrier();

    // ---- Epilogue: wave-local b-slice, full-line coalesced stores ----
    // Instr s: lane l -> row a = 4s + (l>>4), cols 32wv + 2(l&15) (f32x2).
    // Per 16-lane group: 128 B contiguous, 128-B aligned -> full lines.
    float* outp = Kout + (size_t)h * (size_t)L;
    #pragma unroll
    for (int s = 0; s < 8; ++s) {
        const int a = 4 * s + (lane >> 4);
        const int c = 32 * wv + 2 * (lane & 15);
        f32x2 v = *(const f32x2*)&s_out[a][c];
        __builtin_nontemporal_store(v, (f32x2*)&outp[(size_t)a * 128 + c]);
    }
}

extern "C" void kernel_launch(void* const* d_in, const int* in_sizes, int n_in,
                              void* d_out, int out_size, void* d_ws, size_t ws_size,
                              hipStream_t stream) {
    // inputs: [0]=L (int scalar), [1]=log_dt (H,), [2]=C (H,32,2),
    //         [3]=log_A_real (H,32), [4]=A_imag (H,32)
    const float* log_dt     = (const float*)d_in[1];
    const float* Cv         = (const float*)d_in[2];
    const float* log_A_real = (const float*)d_in[3];
    const float* A_imag     = (const float*)d_in[4];
    float* Kout = (float*)d_out;

    const int Hn = in_sizes[1];          // 1024
    const int L  = out_size / Hn;        // 4096 (tiling assumes this)

    dim3 grid(Hn), block(256);
    hipLaunchKernelGGL(s4d_kernel, grid, block, 0, stream,
                       log_dt, Cv, log_A_real, A_imag, Kout, L);
}